// Round 19
// baseline (199.339 us; speedup 1.0000x reference)
//
#include <hip/hip_runtime.h>
#include <hip/hip_bf16.h>
#include <math.h>

#define B_ 16
#define C_ 512
#define H_ 56
#define W_ 56
#define N_ 3136          // H_*W_ = 49*64
#define NH 8
#define HD 64
#define SPLIT 7          // n-split for gram; 3136/7 = 448
#define XPAD 58          // padded x-row stride in floats (bank-spread)

typedef unsigned short bf16;
typedef __attribute__((ext_vector_type(8))) short short8;
typedef __attribute__((ext_vector_type(4))) float f32x4;

__device__ inline float bf2f(unsigned short u) {
    union { unsigned int i; float f; } v; v.i = ((unsigned int)u) << 16; return v.f;
}
// Compiler-native conversion (RNE): pairs get packed into v_cvt_pk_bf16_f32.
__device__ inline unsigned short f2bf(float f) {
    union { __hip_bfloat16 h; unsigned short u; } v;
    v.h = __float2bfloat16(f);
    return v.u;
}

// async global->LDS, 16B per lane, linear dest (wave-uniform base + lane*16)
__device__ inline void load_lds16(const void* g, void* l) {
    __builtin_amdgcn_global_load_lds(
        (const __attribute__((address_space(1))) void*)g,
        (__attribute__((address_space(3))) void*)l, 16, 0, 0);
}

// ---------------------------------------------------------------------------
// Depthwise 3x3 conv + BN. Block = (b_l, ic). x-plane reg-staged into PADDED
// LDS (row stride 58 floats) for ~4-way-max bank spread on halo reads.
// ---------------------------------------------------------------------------
__global__ __launch_bounds__(448) void conv_bn_kernel(
    const float* __restrict__ x, const float* __restrict__ cw,
    const float* __restrict__ gamma, const float* __restrict__ beta,
    const float* __restrict__ mean, const float* __restrict__ var,
    bf16* __restrict__ qkdst, bf16* __restrict__ vdst, int b0)
{
    __shared__ float xs[H_ * XPAD];       // 56*58*4 = 12,992 B
    int bid = blockIdx.x;                 // nb*C_
    int ic = bid & 511; int b_l = bid >> 9;
    int b = b0 + b_l;
    const float* xin = x + ((size_t)b * C_ + ic) * N_;
    int t = threadIdx.x;

    // stage: 784 16B chunks; thread t handles chunk t (+ chunk t+448 if any)
    float4 v0 = *(const float4*)(xin + (size_t)t * 4);
    float4 v1;
    if (t < 336) v1 = *(const float4*)(xin + (size_t)(t + 448) * 4);
    {
        int r = t / 14, cc = t - r * 14;
        float* p = &xs[r * XPAD + cc * 4];
        *(float2*)(p + 0) = make_float2(v0.x, v0.y);
        *(float2*)(p + 2) = make_float2(v0.z, v0.w);
    }
    if (t < 336) {
        int c2 = t + 448;
        int r = c2 / 14, cc = c2 - r * 14;
        float* p = &xs[r * XPAD + cc * 4];
        *(float2*)(p + 0) = make_float2(v1.x, v1.y);
        *(float2*)(p + 2) = make_float2(v1.z, v1.w);
    }

    // block-uniform filter + BN constants (scalar loads)
    float w9[3][9], inv3[3], bias3[3];
#pragma unroll
    for (int ft = 0; ft < 3; ++ft) {
        int o = ic * 3 + ft;
#pragma unroll
        for (int k = 0; k < 9; ++k) w9[ft][k] = cw[o * 9 + k];
        float iv = gamma[o] * rsqrtf(var[o] + 1e-5f);
        inv3[ft] = iv;
        bias3[ft] = fmaf(-mean[o], iv, beta[o]);
    }
    __syncthreads();

    if (t < 392) {
        int yy = t / 7;
        int xx0 = (t - yy * 7) * 8;
        int n0 = t * 8;                   // == yy*56 + xx0
        float vin[3][10];
#pragma unroll
        for (int dy = 0; dy < 3; ++dy) {
            int y2 = yy + dy - 1;
            if (y2 >= 0 && y2 < H_) {
                const float* rp = &xs[y2 * XPAD + xx0];
#pragma unroll
                for (int j = 0; j < 8; ++j) vin[dy][j + 1] = rp[j];
                vin[dy][0] = (xx0 > 0)  ? rp[-1] : 0.f;
                vin[dy][9] = (xx0 < 48) ? rp[8]  : 0.f;
            } else {
#pragma unroll
                for (int j = 0; j < 10; ++j) vin[dy][j] = 0.f;
            }
        }
#pragma unroll
        for (int ft = 0; ft < 3; ++ft) {
            int o = ic * 3 + ft;          // uniform
            int s = o >> 9;               // uniform
            int c = o & 511;
            float r[8];
#pragma unroll
            for (int j = 0; j < 8; ++j) {
                float acc = 0.f;
#pragma unroll
                for (int ky = 0; ky < 3; ++ky)
#pragma unroll
                    for (int kx = 0; kx < 3; ++kx)
                        acc = fmaf(vin[ky][j + kx], w9[ft][ky*3+kx], acc);
                r[j] = fmaf(acc, inv3[ft], bias3[ft]);
            }
            short8 r8;
#pragma unroll
            for (int j = 0; j < 8; ++j) r8[j] = (short)f2bf(r[j]);
            bf16* dst = (s < 2)
                ? qkdst + (((size_t)b_l * 2 + s) * C_ + c) * N_
                : vdst + ((size_t)b_l * C_ + c) * N_;
            *(short8*)(dst + n0) = r8;
        }
    }
}

// ---------------------------------------------------------------------------
// Gram partials via MFMA (T2 swizzle + gload_lds):
//   part[s][bh][d*64+e] = sum_{n in split s} q[d,n]*k[e,n]
// ---------------------------------------------------------------------------
__global__ __launch_bounds__(256) void gram_mfma_kernel(
    const bf16* __restrict__ qk, float* __restrict__ part, int bhTot)
{
    __shared__ bf16 qs[64 * 64];
    __shared__ bf16 ks[64 * 64];
    int bid = blockIdx.x;                 // bhTot*SPLIT
    int s = bid % SPLIT; int bh = bid / SPLIT;
    int h = bh % NH; int b_l = bh / NH;
    const bf16* qp = qk + (((size_t)b_l * 2 + 0) * C_ + h * HD) * N_;
    const bf16* kp = qk + (((size_t)b_l * 2 + 1) * C_ + h * HD) * N_;
    int t = threadIdx.x;
    int w = t >> 6, l = t & 63;
    int r16 = l & 15, kg = l >> 4;
    int wr = w >> 1, wc = w & 1;
    int rsub = l >> 3;
    int colp = ((l & 7) ^ rsub) * 8;      // pre-swizzled n-element offset
    int n0 = s * (N_ / SPLIT);

    f32x4 acc[2][2];
#pragma unroll
    for (int i = 0; i < 2; ++i)
#pragma unroll
        for (int j = 0; j < 2; ++j) acc[i][j] = (f32x4){0.f, 0.f, 0.f, 0.f};

    for (int nc = 0; nc < N_ / SPLIT; nc += 64) {
        int nb = n0 + nc;
#pragma unroll
        for (int i = 0; i < 2; ++i) {
            int row = i * 32 + w * 8 + rsub;
            load_lds16(qp + (size_t)row * N_ + nb + colp, (char*)qs + i * 4096 + t * 16);
            load_lds16(kp + (size_t)row * N_ + nb + colp, (char*)ks + i * 4096 + t * 16);
        }
        __syncthreads();
#pragma unroll
        for (int ksb = 0; ksb < 2; ++ksb) {
            short8 af[2], bfv[2];
#pragma unroll
            for (int mi = 0; mi < 2; ++mi) {
                int row = wr * 32 + mi * 16 + r16;
                int off = row * 128 + ((ksb * 64 + kg * 16) ^ ((row & 7) << 4));
                af[mi] = *(const short8*)((const char*)qs + off);
            }
#pragma unroll
            for (int nj = 0; nj < 2; ++nj) {
                int row = wc * 32 + nj * 16 + r16;
                int off = row * 128 + ((ksb * 64 + kg * 16) ^ ((row & 7) << 4));
                bfv[nj] = *(const short8*)((const char*)ks + off);
            }
#pragma unroll
            for (int mi = 0; mi < 2; ++mi)
#pragma unroll
                for (int nj = 0; nj < 2; ++nj)
                    acc[mi][nj] = __builtin_amdgcn_mfma_f32_16x16x32_bf16(
                        af[mi], bfv[nj], acc[mi][nj], 0, 0, 0);
        }
        __syncthreads();
    }
    float* pp = part + ((size_t)s * bhTot + bh) * 4096;
#pragma unroll
    for (int mi = 0; mi < 2; ++mi)
#pragma unroll
        for (int nj = 0; nj < 2; ++nj) {
            int e = wc * 32 + nj * 16 + r16;
#pragma unroll
            for (int r = 0; r < 4; ++r) {
                int d = wr * 32 + mi * 16 + kg * 4 + r;
                pp[d * 64 + e] = acc[mi][nj][r];
            }
        }
}

// ---------------------------------------------------------------------------
// Reduce partials, scale, softmax over e. One wave per (bh,d) row.
// Writes P TRANSPOSED: PT[bh][e*64+d].
// ---------------------------------------------------------------------------
__global__ __launch_bounds__(64) void softmax_kernel(
    const float* __restrict__ part, float* __restrict__ PT, int bhTot)
{
    int row = blockIdx.x;                 // bh*64 + d
    int e = threadIdx.x;
    size_t base = (size_t)row * 64 + e;
    float val = 0.f;
#pragma unroll
    for (int s = 0; s < SPLIT; ++s) val += part[(size_t)s * bhTot * 4096 + base];
    val *= 0.125f;                        // hd^-0.5
    float m = val;
#pragma unroll
    for (int off = 32; off > 0; off >>= 1) m = fmaxf(m, __shfl_xor(m, off));
    float ex = expf(val - m);
    float sum = ex;
#pragma unroll
    for (int off = 32; off > 0; off >>= 1) sum += __shfl_xor(sum, off);
    PT[(size_t)(row >> 6) * 4096 + (size_t)e * 64 + (row & 63)] = ex / sum;
}

// ---------------------------------------------------------------------------
// outA[b_l][d][h][n] = sum_e PT[e][d] * v[b_l][h*64+e][n]   (bf16 out)
// 128-px tile per block: PT (16KB) staged once serves 2x the output.
// ---------------------------------------------------------------------------
__global__ __launch_bounds__(256) void pv_kernel(
    const bf16* __restrict__ v, const float* __restrict__ PT,
    bf16* __restrict__ outA)
{
    __shared__ float pts[4096];           // PT[e][d] 16KB
    __shared__ bf16 vs[64 * 128];         // vs[e][n] 16KB
    int bid = blockIdx.x;                 // bhTot*25
    int nt = bid % 25; int bh = bid / 25;
    int h = bh % NH, b_l = bh / NH;
    int t = threadIdx.x;
    int nbase = nt * 128;                 // nt=24 tile is partial (3072..3135)
    const float* ptg = PT + (size_t)bh * 4096;
#pragma unroll
    for (int i = 0; i < 4; ++i)
        load_lds16(ptg + i * 1024 + t * 4, (char*)pts + i * 4096 + t * 16);
    const bf16* vb = v + ((size_t)b_l * C_ + h * HD) * N_;
#pragma unroll
    for (int i = 0; i < 4; ++i) {
        int row = i * 16 + (t >> 4);      // e row 0..63
        int n = nbase + (t & 15) * 8;
        if (n > N_ - 8) n = N_ - 8;       // clamp source (dup cols unused)
        load_lds16(vb + (size_t)row * N_ + n,
                   (char*)vs + i * 4096 + (t >> 4) * 256 + (t & 15) * 16);
    }
    __syncthreads();

    int ng = t & 31, dg = t >> 5;         // n-sub = ng*4 (0..127), d0 = dg*8
    float acc[8][4] = {};
#pragma unroll 8
    for (int e = 0; e < 64; ++e) {
        float4 p0 = *(const float4*)&pts[e * 64 + dg * 8];
        float4 p1 = *(const float4*)&pts[e * 64 + dg * 8 + 4];
        ushort4 vv = *(const ushort4*)&vs[e * 128 + ng * 4];
        float v0 = bf2f(vv.x), v1 = bf2f(vv.y), v2 = bf2f(vv.z), v3 = bf2f(vv.w);
        float p8[8] = {p0.x, p0.y, p0.z, p0.w, p1.x, p1.y, p1.z, p1.w};
#pragma unroll
        for (int i = 0; i < 8; ++i) {
            acc[i][0] = fmaf(p8[i], v0, acc[i][0]);
            acc[i][1] = fmaf(p8[i], v1, acc[i][1]);
            acc[i][2] = fmaf(p8[i], v2, acc[i][2]);
            acc[i][3] = fmaf(p8[i], v3, acc[i][3]);
        }
    }
    if (nbase + ng * 4 < N_) {            // 4-aligned, N_ % 4 == 0
        bf16* op = outA + (size_t)b_l * (C_*N_) + (size_t)h * N_ + nbase + ng * 4;
#pragma unroll
        for (int i = 0; i < 8; ++i) {
            ushort4 r4;
            unsigned short* rr = (unsigned short*)&r4;
            rr[0] = f2bf(acc[i][0]); rr[1] = f2bf(acc[i][1]);
            rr[2] = f2bf(acc[i][2]); rr[3] = f2bf(acc[i][3]);
            *(ushort4*)(op + (size_t)(dg * 8 + i) * (NH*N_)) = r4;
        }
    }
}

// ---------------------------------------------------------------------------
// Convert projection weights f32 -> bf16 (512x512).
// ---------------------------------------------------------------------------
__global__ __launch_bounds__(256) void wconv_kernel(
    const float* __restrict__ w, bf16* __restrict__ wb)
{
    int i = blockIdx.x * 256 + threadIdx.x;   // 262144 total
    wb[i] = f2bf(w[i]);
}

// ---------------------------------------------------------------------------
// MFMA projection, 8 waves, tile 128(co) x 256(n), DOUBLE-buffered LDS
// (96KB, 1 block/CU) with T3+T4 counted-vmcnt pipeline: raw s_barrier +
// s_waitcnt vmcnt(6) keeps the next K-tile's 6 loads in flight across the
// barrier (each wave's counted wait covers its own staging contribution).
//   out[b0+b_l][co][n] = sum_c Wb[co][c]*A[b_l][n][c] + pb[co]
// ---------------------------------------------------------------------------
__global__ __launch_bounds__(512) void proj_mfma_kernel(
    const bf16* __restrict__ A, const bf16* __restrict__ Wb,
    const float* __restrict__ bias, float* __restrict__ out, int b0, int nwg)
{
    __shared__ bf16 Ws_s[2][128 * 64];    // 2 x 16 KB
    __shared__ bf16 As_s[2][256 * 64];    // 2 x 32 KB
    int bid = blockIdx.x;                 // nwg = nb*52, nwg % 8 == 0
    int cpx = nwg >> 3;                   // chunk per XCD (104: % 4 == 0)
    int swz = (bid & 7) * cpx + (bid >> 3);
    int b_l = swz / 52; int rem = swz % 52;
    int nt = rem >> 2, mt = rem & 3;      // mt fastest: A-quad on one XCD
    int m0 = mt * 128, n0 = nt * 256;     // nt in 0..12
    int t = threadIdx.x;
    int w = t >> 6, l = t & 63;
    int r16 = l & 15, kg = l >> 4;        // frag row / k-group
    int wr = w >> 2, wc = w & 3;          // wave quadrant: 2 co x 4 n
    const bf16* Ab = A + (size_t)b_l * N_ * C_;
    int srow = t >> 3;                    // staging row within 64-row chunk
    int colp = ((t & 7) ^ (srow & 7)) * 8;// pre-swizzled k-element offset

    f32x4 acc[4][4];
#pragma unroll
    for (int i = 0; i < 4; ++i)
#pragma unroll
        for (int j = 0; j < 4; ++j) acc[i][j] = (f32x4){0.f, 0.f, 0.f, 0.f};

#define PSTAGE(BUF, K0)                                                       \
    do {                                                                      \
        _Pragma("unroll")                                                     \
        for (int i = 0; i < 2; ++i) {                                         \
            int row = i * 64 + srow;                                          \
            load_lds16(Wb + (size_t)(m0 + row) * C_ + (K0) + colp,            \
                       (char*)Ws_s[BUF] + i * 8192 + t * 16);                 \
        }                                                                     \
        _Pragma("unroll")                                                     \
        for (int i = 0; i < 4; ++i) {                                         \
            int row = i * 64 + srow;                                          \
            int nn = n0 + row; if (nn >= N_) nn = N_ - 1;                     \
            load_lds16(Ab + (size_t)nn * C_ + (K0) + colp,                    \
                       (char*)As_s[BUF] + i * 8192 + t * 16);                 \
        }                                                                     \
    } while (0)

#define PCOMPUTE(BUF)                                                         \
    do {                                                                      \
        _Pragma("unroll")                                                     \
        for (int ks = 0; ks < 2; ++ks) {                                      \
            short8 af[4], bfv[4];                                             \
            _Pragma("unroll")                                                 \
            for (int mi = 0; mi < 4; ++mi) {                                  \
                int row = wr * 64 + mi * 16 + r16;                            \
                int off = row * 128 + ((ks * 64 + kg * 16) ^ ((row & 7) << 4)); \
                af[mi] = *(const short8*)((const char*)Ws_s[BUF] + off);      \
            }                                                                 \
            _Pragma("unroll")                                                 \
            for (int nj = 0; nj < 4; ++nj) {                                  \
                int row = wc * 64 + nj * 16 + r16;                            \
                int off = row * 128 + ((ks * 64 + kg * 16) ^ ((row & 7) << 4)); \
                bfv[nj] = *(const short8*)((const char*)As_s[BUF] + off);     \
            }                                                                 \
            _Pragma("unroll")                                                 \
            for (int mi = 0; mi < 4; ++mi)                                    \
                _Pragma("unroll")                                             \
                for (int nj = 0; nj < 4; ++nj)                                \
                    acc[mi][nj] = __builtin_amdgcn_mfma_f32_16x16x32_bf16(    \
                        af[mi], bfv[nj], acc[mi][nj], 0, 0, 0);               \
        }                                                                     \
    } while (0)

    PSTAGE(0, 0);
    PSTAGE(1, 64);
#pragma unroll
    for (int k = 0; k < 8; ++k) {
        // wait for buf[k&1]'s 6 loads (older); keep next stage's 6 in flight
        if (k < 7) asm volatile("s_waitcnt vmcnt(6)" ::: "memory");
        else       asm volatile("s_waitcnt vmcnt(0)" ::: "memory");
        __builtin_amdgcn_sched_barrier(0);
        __builtin_amdgcn_s_barrier();     // all waves confirmed their share
        PCOMPUTE(k & 1);
        __builtin_amdgcn_s_barrier();     // all reads of buf[k&1] done
        __builtin_amdgcn_sched_barrier(0);
        if (k < 6) PSTAGE(k & 1, (k + 2) * 64);
    }

    float* ob = out + ((size_t)(b0 + b_l) * C_) * N_;
#pragma unroll
    for (int mi = 0; mi < 4; ++mi) {
        int cobase = m0 + wr * 64 + mi * 16 + kg * 4;
#pragma unroll
        for (int r = 0; r < 4; ++r) {
            int co = cobase + r;
            float bi = bias[co];
#pragma unroll
            for (int nj = 0; nj < 4; ++nj) {
                int n = n0 + wc * 64 + nj * 16 + r16;
                if (n < N_) ob[(size_t)co * N_ + n] = acc[mi][nj][r] + bi;
            }
        }
    }
#undef PSTAGE
#undef PCOMPUTE
}

extern "C" void kernel_launch(void* const* d_in, const int* in_sizes, int n_in,
                              void* d_out, int out_size, void* d_ws, size_t ws_size,
                              hipStream_t stream) {
    const float* x     = (const float*)d_in[0];
    const float* cw    = (const float*)d_in[1];
    const float* gamma = (const float*)d_in[2];
    const float* beta  = (const float*)d_in[3];
    const float* mean  = (const float*)d_in[4];
    const float* var   = (const float*)d_in[5];
    const float* pw    = (const float*)d_in[6];
    const float* pb    = (const float*)d_in[7];
    float* out = (float*)d_out;
    char* wsp = (char*)d_ws;

    const size_t W_B = (size_t)C_ * C_ * sizeof(bf16);              // 524,288

    // Single-pass (all 16 batches) if workspace allows; else two passes of 8.
    size_t qk16   = (size_t)16 * 2 * C_ * N_ * sizeof(bf16);        // 102.8 MB
    size_t v16    = (size_t)16 * C_ * N_ * sizeof(bf16);            //  51.4 MB
    size_t part16 = (size_t)SPLIT * 16 * NH * 4096 * 4;             //  14.7 MB
    size_t pt16   = (size_t)16 * NH * 4096 * 4;                     //   2.1 MB

    int nbs[2]; int ngroups;
    if (ws_size >= qk16 + v16 + part16 + pt16 + W_B) {
        ngroups = 1; nbs[0] = 16;
    } else {
        ngroups = 2; nbs[0] = 8; nbs[1] = 8;
    }

    int b0 = 0;
    for (int gi = 0; gi < ngroups; ++gi) {
        int nb = nbs[gi];
        size_t QK_B   = (size_t)nb * 2 * C_ * N_ * sizeof(bf16);
        size_t V_B    = (size_t)nb * C_ * N_ * sizeof(bf16);
        size_t PART_B = (size_t)SPLIT * nb * NH * 4096 * 4;
        size_t PT_B   = (size_t)nb * NH * 4096 * 4;
        bf16*  qk   = (bf16*)wsp;
        bf16*  v    = (bf16*)(wsp + QK_B);
        float* part = (float*)(wsp + QK_B + V_B);
        float* PT   = (float*)(wsp + QK_B + V_B + PART_B);
        bf16*  Wbf  = (bf16*)(wsp + QK_B + V_B + PART_B + PT_B);
        bf16*  outA = qk;                  // reuse q,k region after gram
        int bhTot = nb * NH;

        if (gi == 0)
            wconv_kernel<<<(C_ * C_) / 256, 256, 0, stream>>>(pw, Wbf);

        conv_bn_kernel<<<nb * C_, 448, 0, stream>>>(
            x, cw, gamma, beta, mean, var, qk, v, b0);
        gram_mfma_kernel<<<bhTot * SPLIT, 256, 0, stream>>>(qk, part, bhTot);
        softmax_kernel<<<bhTot * 64, 64, 0, stream>>>(part, PT, bhTot);
        pv_kernel<<<bhTot * 25, 256, 0, stream>>>(v, PT, outA);
        proj_mfma_kernel<<<nb * 52, 512, 0, stream>>>(outA, Wbf, pb, out, b0, nb * 52);
        b0 += nb;
    }
}

// Round 20
// 175.025 us; speedup vs baseline: 1.1389x; 1.1389x over previous
//
#include <hip/hip_runtime.h>
#include <hip/hip_bf16.h>
#include <math.h>

#define B_ 16
#define C_ 512
#define H_ 56
#define W_ 56
#define N_ 3136          // H_*W_ = 49*64
#define NH 8
#define HD 64
#define SPLIT 7          // n-split for gram; 3136/7 = 448
#define XPAD 58          // padded x-row stride in floats (bank-spread)

typedef unsigned short bf16;
typedef __attribute__((ext_vector_type(8))) short short8;
typedef __attribute__((ext_vector_type(4))) float f32x4;

__device__ inline float bf2f(unsigned short u) {
    union { unsigned int i; float f; } v; v.i = ((unsigned int)u) << 16; return v.f;
}
// Compiler-native conversion (RNE): pairs get packed into v_cvt_pk_bf16_f32.
__device__ inline unsigned short f2bf(float f) {
    union { __hip_bfloat16 h; unsigned short u; } v;
    v.h = __float2bfloat16(f);
    return v.u;
}

// async global->LDS, 16B per lane, linear dest (wave-uniform base + lane*16)
__device__ inline void load_lds16(const void* g, void* l) {
    __builtin_amdgcn_global_load_lds(
        (const __attribute__((address_space(1))) void*)g,
        (__attribute__((address_space(3))) void*)l, 16, 0, 0);
}

// ---------------------------------------------------------------------------
// Depthwise 3x3 conv + BN. Block = (b_l, ic). x-plane reg-staged into PADDED
// LDS (row stride 58 floats) for ~4-way-max bank spread on halo reads.
// ---------------------------------------------------------------------------
__global__ __launch_bounds__(448) void conv_bn_kernel(
    const float* __restrict__ x, const float* __restrict__ cw,
    const float* __restrict__ gamma, const float* __restrict__ beta,
    const float* __restrict__ mean, const float* __restrict__ var,
    bf16* __restrict__ qkdst, bf16* __restrict__ vdst, int b0)
{
    __shared__ float xs[H_ * XPAD];       // 56*58*4 = 12,992 B
    int bid = blockIdx.x;                 // nb*C_
    int ic = bid & 511; int b_l = bid >> 9;
    int b = b0 + b_l;
    const float* xin = x + ((size_t)b * C_ + ic) * N_;
    int t = threadIdx.x;

    // stage: 784 16B chunks; thread t handles chunk t (+ chunk t+448 if any)
    float4 v0 = *(const float4*)(xin + (size_t)t * 4);
    float4 v1;
    if (t < 336) v1 = *(const float4*)(xin + (size_t)(t + 448) * 4);
    {
        int r = t / 14, cc = t - r * 14;
        float* p = &xs[r * XPAD + cc * 4];
        *(float2*)(p + 0) = make_float2(v0.x, v0.y);
        *(float2*)(p + 2) = make_float2(v0.z, v0.w);
    }
    if (t < 336) {
        int c2 = t + 448;
        int r = c2 / 14, cc = c2 - r * 14;
        float* p = &xs[r * XPAD + cc * 4];
        *(float2*)(p + 0) = make_float2(v1.x, v1.y);
        *(float2*)(p + 2) = make_float2(v1.z, v1.w);
    }

    // block-uniform filter + BN constants (scalar loads)
    float w9[3][9], inv3[3], bias3[3];
#pragma unroll
    for (int ft = 0; ft < 3; ++ft) {
        int o = ic * 3 + ft;
#pragma unroll
        for (int k = 0; k < 9; ++k) w9[ft][k] = cw[o * 9 + k];
        float iv = gamma[o] * rsqrtf(var[o] + 1e-5f);
        inv3[ft] = iv;
        bias3[ft] = fmaf(-mean[o], iv, beta[o]);
    }
    __syncthreads();

    if (t < 392) {
        int yy = t / 7;
        int xx0 = (t - yy * 7) * 8;
        int n0 = t * 8;                   // == yy*56 + xx0
        float vin[3][10];
#pragma unroll
        for (int dy = 0; dy < 3; ++dy) {
            int y2 = yy + dy - 1;
            if (y2 >= 0 && y2 < H_) {
                const float* rp = &xs[y2 * XPAD + xx0];
#pragma unroll
                for (int j = 0; j < 8; ++j) vin[dy][j + 1] = rp[j];
                vin[dy][0] = (xx0 > 0)  ? rp[-1] : 0.f;
                vin[dy][9] = (xx0 < 48) ? rp[8]  : 0.f;
            } else {
#pragma unroll
                for (int j = 0; j < 10; ++j) vin[dy][j] = 0.f;
            }
        }
#pragma unroll
        for (int ft = 0; ft < 3; ++ft) {
            int o = ic * 3 + ft;          // uniform
            int s = o >> 9;               // uniform
            int c = o & 511;
            float r[8];
#pragma unroll
            for (int j = 0; j < 8; ++j) {
                float acc = 0.f;
#pragma unroll
                for (int ky = 0; ky < 3; ++ky)
#pragma unroll
                    for (int kx = 0; kx < 3; ++kx)
                        acc = fmaf(vin[ky][j + kx], w9[ft][ky*3+kx], acc);
                r[j] = fmaf(acc, inv3[ft], bias3[ft]);
            }
            short8 r8;
#pragma unroll
            for (int j = 0; j < 8; ++j) r8[j] = (short)f2bf(r[j]);
            bf16* dst = (s < 2)
                ? qkdst + (((size_t)b_l * 2 + s) * C_ + c) * N_
                : vdst + ((size_t)b_l * C_ + c) * N_;
            *(short8*)(dst + n0) = r8;
        }
    }
}

// ---------------------------------------------------------------------------
// Gram partials via MFMA (T2 swizzle + gload_lds):
//   part[s][bh][d*64+e] = sum_{n in split s} q[d,n]*k[e,n]
// ---------------------------------------------------------------------------
__global__ __launch_bounds__(256) void gram_mfma_kernel(
    const bf16* __restrict__ qk, float* __restrict__ part, int bhTot)
{
    __shared__ bf16 qs[64 * 64];
    __shared__ bf16 ks[64 * 64];
    int bid = blockIdx.x;                 // bhTot*SPLIT
    int s = bid % SPLIT; int bh = bid / SPLIT;
    int h = bh % NH; int b_l = bh / NH;
    const bf16* qp = qk + (((size_t)b_l * 2 + 0) * C_ + h * HD) * N_;
    const bf16* kp = qk + (((size_t)b_l * 2 + 1) * C_ + h * HD) * N_;
    int t = threadIdx.x;
    int w = t >> 6, l = t & 63;
    int r16 = l & 15, kg = l >> 4;
    int wr = w >> 1, wc = w & 1;
    int rsub = l >> 3;
    int colp = ((l & 7) ^ rsub) * 8;      // pre-swizzled n-element offset
    int n0 = s * (N_ / SPLIT);

    f32x4 acc[2][2];
#pragma unroll
    for (int i = 0; i < 2; ++i)
#pragma unroll
        for (int j = 0; j < 2; ++j) acc[i][j] = (f32x4){0.f, 0.f, 0.f, 0.f};

    for (int nc = 0; nc < N_ / SPLIT; nc += 64) {
        int nb = n0 + nc;
#pragma unroll
        for (int i = 0; i < 2; ++i) {
            int row = i * 32 + w * 8 + rsub;
            load_lds16(qp + (size_t)row * N_ + nb + colp, (char*)qs + i * 4096 + t * 16);
            load_lds16(kp + (size_t)row * N_ + nb + colp, (char*)ks + i * 4096 + t * 16);
        }
        __syncthreads();
#pragma unroll
        for (int ksb = 0; ksb < 2; ++ksb) {
            short8 af[2], bfv[2];
#pragma unroll
            for (int mi = 0; mi < 2; ++mi) {
                int row = wr * 32 + mi * 16 + r16;
                int off = row * 128 + ((ksb * 64 + kg * 16) ^ ((row & 7) << 4));
                af[mi] = *(const short8*)((const char*)qs + off);
            }
#pragma unroll
            for (int nj = 0; nj < 2; ++nj) {
                int row = wc * 32 + nj * 16 + r16;
                int off = row * 128 + ((ksb * 64 + kg * 16) ^ ((row & 7) << 4));
                bfv[nj] = *(const short8*)((const char*)ks + off);
            }
#pragma unroll
            for (int mi = 0; mi < 2; ++mi)
#pragma unroll
                for (int nj = 0; nj < 2; ++nj)
                    acc[mi][nj] = __builtin_amdgcn_mfma_f32_16x16x32_bf16(
                        af[mi], bfv[nj], acc[mi][nj], 0, 0, 0);
        }
        __syncthreads();
    }
    float* pp = part + ((size_t)s * bhTot + bh) * 4096;
#pragma unroll
    for (int mi = 0; mi < 2; ++mi)
#pragma unroll
        for (int nj = 0; nj < 2; ++nj) {
            int e = wc * 32 + nj * 16 + r16;
#pragma unroll
            for (int r = 0; r < 4; ++r) {
                int d = wr * 32 + mi * 16 + kg * 4 + r;
                pp[d * 64 + e] = acc[mi][nj][r];
            }
        }
}

// ---------------------------------------------------------------------------
// Softmax, one block per bh (256 threads). Thread t owns elements
// [16t, 16t+16) of the 4096-elem tile = row d=t/4, e-range (t%4)*16..+16.
// Row reduce via shfl_xor(1/2) in the 4-lane group; LDS transpose [64][65]
// (padded, conflict-free); coalesced float4 PT write.
// ---------------------------------------------------------------------------
__global__ __launch_bounds__(256) void softmax_kernel(
    const float* __restrict__ part, float* __restrict__ PT, int bhTot)
{
    __shared__ float tr[64][65];
    int bh = blockIdx.x;
    int t = threadIdx.x;
    int d = t >> 2;                       // 0..63
    int e0 = (t & 3) * 16;
    size_t base = (size_t)bh * 4096 + (size_t)t * 16;   // == d*64 + e0
    float val[16];
#pragma unroll
    for (int j = 0; j < 16; j += 4) {
        float4 a = *(const float4*)&part[base + j];
        val[j] = a.x; val[j+1] = a.y; val[j+2] = a.z; val[j+3] = a.w;
    }
    for (int s = 1; s < SPLIT; ++s) {
        size_t off = (size_t)s * bhTot * 4096 + base;
#pragma unroll
        for (int j = 0; j < 16; j += 4) {
            float4 a = *(const float4*)&part[off + j];
            val[j] += a.x; val[j+1] += a.y; val[j+2] += a.z; val[j+3] += a.w;
        }
    }
    float m = -1e30f;
#pragma unroll
    for (int j = 0; j < 16; ++j) { val[j] *= 0.125f; m = fmaxf(m, val[j]); }
    m = fmaxf(m, __shfl_xor(m, 1));
    m = fmaxf(m, __shfl_xor(m, 2));
    float sum = 0.f;
#pragma unroll
    for (int j = 0; j < 16; ++j) { val[j] = expf(val[j] - m); sum += val[j]; }
    sum += __shfl_xor(sum, 1);
    sum += __shfl_xor(sum, 2);
    float inv = 1.f / sum;
#pragma unroll
    for (int j = 0; j < 16; ++j) tr[e0 + j][d] = val[j] * inv;
    __syncthreads();
    float* op = PT + (size_t)bh * 4096 + (size_t)t * 16;
    int e = t >> 2, d0 = (t & 3) * 16;
#pragma unroll
    for (int j = 0; j < 16; j += 4) {
        float4 r;
        r.x = tr[e][d0+j];   r.y = tr[e][d0+j+1];
        r.z = tr[e][d0+j+2]; r.w = tr[e][d0+j+3];
        *(float4*)(op + j) = r;
    }
}

// ---------------------------------------------------------------------------
// outA[b_l][d][h][n] = sum_e PT[e][d] * v[b_l][h*64+e][n]   (bf16 out)
// 128-px tile per block: PT (16KB) staged once serves 2x the output.
// ---------------------------------------------------------------------------
__global__ __launch_bounds__(256) void pv_kernel(
    const bf16* __restrict__ v, const float* __restrict__ PT,
    bf16* __restrict__ outA)
{
    __shared__ float pts[4096];           // PT[e][d] 16KB
    __shared__ bf16 vs[64 * 128];         // vs[e][n] 16KB
    int bid = blockIdx.x;                 // bhTot*25
    int nt = bid % 25; int bh = bid / 25;
    int h = bh % NH, b_l = bh / NH;
    int t = threadIdx.x;
    int nbase = nt * 128;                 // nt=24 tile is partial (3072..3135)
    const float* ptg = PT + (size_t)bh * 4096;
#pragma unroll
    for (int i = 0; i < 4; ++i)
        load_lds16(ptg + i * 1024 + t * 4, (char*)pts + i * 4096 + t * 16);
    const bf16* vb = v + ((size_t)b_l * C_ + h * HD) * N_;
#pragma unroll
    for (int i = 0; i < 4; ++i) {
        int row = i * 16 + (t >> 4);      // e row 0..63
        int n = nbase + (t & 15) * 8;
        if (n > N_ - 8) n = N_ - 8;       // clamp source (dup cols unused)
        load_lds16(vb + (size_t)row * N_ + n,
                   (char*)vs + i * 4096 + (t >> 4) * 256 + (t & 15) * 16);
    }
    __syncthreads();

    int ng = t & 31, dg = t >> 5;         // n-sub = ng*4 (0..127), d0 = dg*8
    float acc[8][4] = {};
#pragma unroll 8
    for (int e = 0; e < 64; ++e) {
        float4 p0 = *(const float4*)&pts[e * 64 + dg * 8];
        float4 p1 = *(const float4*)&pts[e * 64 + dg * 8 + 4];
        ushort4 vv = *(const ushort4*)&vs[e * 128 + ng * 4];
        float v0 = bf2f(vv.x), v1 = bf2f(vv.y), v2 = bf2f(vv.z), v3 = bf2f(vv.w);
        float p8[8] = {p0.x, p0.y, p0.z, p0.w, p1.x, p1.y, p1.z, p1.w};
#pragma unroll
        for (int i = 0; i < 8; ++i) {
            acc[i][0] = fmaf(p8[i], v0, acc[i][0]);
            acc[i][1] = fmaf(p8[i], v1, acc[i][1]);
            acc[i][2] = fmaf(p8[i], v2, acc[i][2]);
            acc[i][3] = fmaf(p8[i], v3, acc[i][3]);
        }
    }
    if (nbase + ng * 4 < N_) {            // 4-aligned, N_ % 4 == 0
        bf16* op = outA + (size_t)b_l * (C_*N_) + (size_t)h * N_ + nbase + ng * 4;
#pragma unroll
        for (int i = 0; i < 8; ++i) {
            ushort4 r4;
            unsigned short* rr = (unsigned short*)&r4;
            rr[0] = f2bf(acc[i][0]); rr[1] = f2bf(acc[i][1]);
            rr[2] = f2bf(acc[i][2]); rr[3] = f2bf(acc[i][3]);
            *(ushort4*)(op + (size_t)(dg * 8 + i) * (NH*N_)) = r4;
        }
    }
}

// ---------------------------------------------------------------------------
// Convert projection weights f32 -> bf16 (512x512).
// ---------------------------------------------------------------------------
__global__ __launch_bounds__(256) void wconv_kernel(
    const float* __restrict__ w, bf16* __restrict__ wb)
{
    int i = blockIdx.x * 256 + threadIdx.x;   // 262144 total
    wb[i] = f2bf(w[i]);
}

// ---------------------------------------------------------------------------
// MFMA projection, 8 waves, tile 128(co) x 256(n), single-buffered LDS
// (48KB), XCD-chunked swizzle with mt fastest. (Round-18 version — both
// explicit-pipeline variants regressed via occupancy; single buffer +
// implicit multi-block overlap is the local optimum for this shape.)
//   out[b0+b_l][co][n] = sum_c Wb[co][c]*A[b_l][n][c] + pb[co]
// ---------------------------------------------------------------------------
__global__ __launch_bounds__(512) void proj_mfma_kernel(
    const bf16* __restrict__ A, const bf16* __restrict__ Wb,
    const float* __restrict__ bias, float* __restrict__ out, int b0, int nwg)
{
    __shared__ bf16 Ws_s[128 * 64];       // 16 KB
    __shared__ bf16 As_s[256 * 64];       // 32 KB
    int bid = blockIdx.x;                 // nwg = nb*52, nwg % 8 == 0
    int cpx = nwg >> 3;                   // chunk per XCD (104: % 4 == 0)
    int swz = (bid & 7) * cpx + (bid >> 3);
    int b_l = swz / 52; int rem = swz % 52;
    int nt = rem >> 2, mt = rem & 3;      // mt fastest: A-quad on one XCD
    int m0 = mt * 128, n0 = nt * 256;     // nt in 0..12
    int t = threadIdx.x;
    int w = t >> 6, l = t & 63;
    int r16 = l & 15, kg = l >> 4;        // frag row / k-group
    int wr = w >> 2, wc = w & 3;          // wave quadrant: 2 co x 4 n
    const bf16* Ab = A + (size_t)b_l * N_ * C_;
    int srow = t >> 3;                    // staging row within 64-row chunk
    int colp = ((t & 7) ^ (srow & 7)) * 8;// pre-swizzled k-element offset

    f32x4 acc[4][4];
#pragma unroll
    for (int i = 0; i < 4; ++i)
#pragma unroll
        for (int j = 0; j < 4; ++j) acc[i][j] = (f32x4){0.f, 0.f, 0.f, 0.f};

    for (int k0 = 0; k0 < C_; k0 += 64) {
#pragma unroll
        for (int i = 0; i < 2; ++i) {
            int row = i * 64 + srow;
            load_lds16(Wb + (size_t)(m0 + row) * C_ + k0 + colp,
                       (char*)Ws_s + i * 8192 + t * 16);
        }
#pragma unroll
        for (int i = 0; i < 4; ++i) {
            int row = i * 64 + srow;
            int nn = n0 + row; if (nn >= N_) nn = N_ - 1;
            load_lds16(Ab + (size_t)nn * C_ + k0 + colp,
                       (char*)As_s + i * 8192 + t * 16);
        }
        __syncthreads();
#pragma unroll
        for (int ks = 0; ks < 2; ++ks) {
            short8 af[4], bfv[4];
#pragma unroll
            for (int mi = 0; mi < 4; ++mi) {
                int row = wr * 64 + mi * 16 + r16;
                int off = row * 128 + ((ks * 64 + kg * 16) ^ ((row & 7) << 4));
                af[mi] = *(const short8*)((const char*)Ws_s + off);
            }
#pragma unroll
            for (int nj = 0; nj < 4; ++nj) {
                int row = wc * 64 + nj * 16 + r16;
                int off = row * 128 + ((ks * 64 + kg * 16) ^ ((row & 7) << 4));
                bfv[nj] = *(const short8*)((const char*)As_s + off);
            }
#pragma unroll
            for (int mi = 0; mi < 4; ++mi)
#pragma unroll
                for (int nj = 0; nj < 4; ++nj)
                    acc[mi][nj] = __builtin_amdgcn_mfma_f32_16x16x32_bf16(
                        af[mi], bfv[nj], acc[mi][nj], 0, 0, 0);
        }
        __syncthreads();
    }
    float* ob = out + ((size_t)(b0 + b_l) * C_) * N_;
#pragma unroll
    for (int mi = 0; mi < 4; ++mi) {
        int cobase = m0 + wr * 64 + mi * 16 + kg * 4;
#pragma unroll
        for (int r = 0; r < 4; ++r) {
            int co = cobase + r;
            float bi = bias[co];
#pragma unroll
            for (int nj = 0; nj < 4; ++nj) {
                int n = n0 + wc * 64 + nj * 16 + r16;
                if (n < N_) ob[(size_t)co * N_ + n] = acc[mi][nj][r] + bi;
            }
        }
    }
}

extern "C" void kernel_launch(void* const* d_in, const int* in_sizes, int n_in,
                              void* d_out, int out_size, void* d_ws, size_t ws_size,
                              hipStream_t stream) {
    const float* x     = (const float*)d_in[0];
    const float* cw    = (const float*)d_in[1];
    const float* gamma = (const float*)d_in[2];
    const float* beta  = (const float*)d_in[3];
    const float* mean  = (const float*)d_in[4];
    const float* var   = (const float*)d_in[5];
    const float* pw    = (const float*)d_in[6];
    const float* pb    = (const float*)d_in[7];
    float* out = (float*)d_out;
    char* wsp = (char*)d_ws;

    const size_t W_B = (size_t)C_ * C_ * sizeof(bf16);              // 524,288

    // Single-pass (all 16 batches) if workspace allows; else two passes of 8.
    size_t qk16   = (size_t)16 * 2 * C_ * N_ * sizeof(bf16);        // 102.8 MB
    size_t v16    = (size_t)16 * C_ * N_ * sizeof(bf16);            //  51.4 MB
    size_t part16 = (size_t)SPLIT * 16 * NH * 4096 * 4;             //  14.7 MB
    size_t pt16   = (size_t)16 * NH * 4096 * 4;                     //   2.1 MB

    int nbs[2]; int ngroups;
    if (ws_size >= qk16 + v16 + part16 + pt16 + W_B) {
        ngroups = 1; nbs[0] = 16;
    } else {
        ngroups = 2; nbs[0] = 8; nbs[1] = 8;
    }

    int b0 = 0;
    for (int gi = 0; gi < ngroups; ++gi) {
        int nb = nbs[gi];
        size_t QK_B   = (size_t)nb * 2 * C_ * N_ * sizeof(bf16);
        size_t V_B    = (size_t)nb * C_ * N_ * sizeof(bf16);
        size_t PART_B = (size_t)SPLIT * nb * NH * 4096 * 4;
        size_t PT_B   = (size_t)nb * NH * 4096 * 4;
        bf16*  qk   = (bf16*)wsp;
        bf16*  v    = (bf16*)(wsp + QK_B);
        float* part = (float*)(wsp + QK_B + V_B);
        float* PT   = (float*)(wsp + QK_B + V_B + PART_B);
        bf16*  Wbf  = (bf16*)(wsp + QK_B + V_B + PART_B + PT_B);
        bf16*  outA = qk;                  // reuse q,k region after gram
        int bhTot = nb * NH;

        if (gi == 0)
            wconv_kernel<<<(C_ * C_) / 256, 256, 0, stream>>>(pw, Wbf);

        conv_bn_kernel<<<nb * C_, 448, 0, stream>>>(
            x, cw, gamma, beta, mean, var, qk, v, b0);
        gram_mfma_kernel<<<bhTot * SPLIT, 256, 0, stream>>>(qk, part, bhTot);
        softmax_kernel<<<bhTot, 256, 0, stream>>>(part, PT, bhTot);
        pv_kernel<<<bhTot * 25, 256, 0, stream>>>(v, PT, outA);
        proj_mfma_kernel<<<nb * 52, 512, 0, stream>>>(outA, Wbf, pb, out, b0, nb * 52);
        b0 += nb;
    }
}

// Round 21
// 173.767 us; speedup vs baseline: 1.1472x; 1.0072x over previous
//
#include <hip/hip_runtime.h>
#include <hip/hip_bf16.h>
#include <math.h>

#define B_ 16
#define C_ 512
#define H_ 56
#define W_ 56
#define N_ 3136          // H_*W_ = 49*64
#define NH 8
#define HD 64
#define SPLIT 7          // n-split for gram; 3136/7 = 448
#define XPAD 58          // padded x-row stride in floats (bank-spread)

typedef unsigned short bf16;
typedef __attribute__((ext_vector_type(8))) short short8;
typedef __attribute__((ext_vector_type(4))) float f32x4;

__device__ inline float bf2f(unsigned short u) {
    union { unsigned int i; float f; } v; v.i = ((unsigned int)u) << 16; return v.f;
}
// Compiler-native conversion (RNE): pairs get packed into v_cvt_pk_bf16_f32.
__device__ inline unsigned short f2bf(float f) {
    union { __hip_bfloat16 h; unsigned short u; } v;
    v.h = __float2bfloat16(f);
    return v.u;
}

// async global->LDS, 16B per lane, linear dest (wave-uniform base + lane*16)
__device__ inline void load_lds16(const void* g, void* l) {
    __builtin_amdgcn_global_load_lds(
        (const __attribute__((address_space(1))) void*)g,
        (__attribute__((address_space(3))) void*)l, 16, 0, 0);
}

// ---------------------------------------------------------------------------
// Depthwise 3x3 conv + BN. Block = (b_l, ic). Thread t stages ITS OWN middle
// row (float4 at n0, n0+4 — coalesced 32B/thread) -> kept in registers AND
// written to padded LDS for neighbors' halo reads. Middle row costs no LDS
// read; only halo rows (dy=0,2) + 2 edge scalars come from LDS.
// ---------------------------------------------------------------------------
__global__ __launch_bounds__(448) void conv_bn_kernel(
    const float* __restrict__ x, const float* __restrict__ cw,
    const float* __restrict__ gamma, const float* __restrict__ beta,
    const float* __restrict__ mean, const float* __restrict__ var,
    bf16* __restrict__ qkdst, bf16* __restrict__ vdst, int b0)
{
    __shared__ float xs[H_ * XPAD];       // 56*58*4 = 12,992 B
    int bid = blockIdx.x;                 // nb*C_
    int ic = bid & 511; int b_l = bid >> 9;
    int b = b0 + b_l;
    const float* xin = x + ((size_t)b * C_ + ic) * N_;
    int t = threadIdx.x;

    int yy = 0, xx0 = 0, n0 = 0;
    float mr[8];                          // middle row in registers
    if (t < 392) {
        yy = t / 7;
        xx0 = (t - yy * 7) * 8;
        n0 = t * 8;                       // == yy*56 + xx0
        float4 a = *(const float4*)(xin + n0);
        float4 c4 = *(const float4*)(xin + n0 + 4);
        mr[0]=a.x;  mr[1]=a.y;  mr[2]=a.z;  mr[3]=a.w;
        mr[4]=c4.x; mr[5]=c4.y; mr[6]=c4.z; mr[7]=c4.w;
        float* p = &xs[yy * XPAD + xx0];
        *(float2*)(p + 0) = make_float2(mr[0], mr[1]);
        *(float2*)(p + 2) = make_float2(mr[2], mr[3]);
        *(float2*)(p + 4) = make_float2(mr[4], mr[5]);
        *(float2*)(p + 6) = make_float2(mr[6], mr[7]);
    }

    // block-uniform filter + BN constants (scalar loads)
    float w9[3][9], inv3[3], bias3[3];
#pragma unroll
    for (int ft = 0; ft < 3; ++ft) {
        int o = ic * 3 + ft;
#pragma unroll
        for (int k = 0; k < 9; ++k) w9[ft][k] = cw[o * 9 + k];
        float iv = gamma[o] * rsqrtf(var[o] + 1e-5f);
        inv3[ft] = iv;
        bias3[ft] = fmaf(-mean[o], iv, beta[o]);
    }
    __syncthreads();

    if (t < 392) {
        float vin[3][10];
        // middle row: registers + 2 LDS edge scalars
#pragma unroll
        for (int j = 0; j < 8; ++j) vin[1][j + 1] = mr[j];
        vin[1][0] = (xx0 > 0)  ? xs[yy * XPAD + xx0 - 1] : 0.f;
        vin[1][9] = (xx0 < 48) ? xs[yy * XPAD + xx0 + 8] : 0.f;
        // halo rows from LDS
#pragma unroll
        for (int dy = 0; dy < 3; dy += 2) {
            int y2 = yy + dy - 1;
            if (y2 >= 0 && y2 < H_) {
                const float* rp = &xs[y2 * XPAD + xx0];
#pragma unroll
                for (int j = 0; j < 8; ++j) vin[dy][j + 1] = rp[j];
                vin[dy][0] = (xx0 > 0)  ? rp[-1] : 0.f;
                vin[dy][9] = (xx0 < 48) ? rp[8]  : 0.f;
            } else {
#pragma unroll
                for (int j = 0; j < 10; ++j) vin[dy][j] = 0.f;
            }
        }
#pragma unroll
        for (int ft = 0; ft < 3; ++ft) {
            int o = ic * 3 + ft;          // uniform
            int s = o >> 9;               // uniform
            int c = o & 511;
            float r[8];
#pragma unroll
            for (int j = 0; j < 8; ++j) {
                float acc = 0.f;
#pragma unroll
                for (int ky = 0; ky < 3; ++ky)
#pragma unroll
                    for (int kx = 0; kx < 3; ++kx)
                        acc = fmaf(vin[ky][j + kx], w9[ft][ky*3+kx], acc);
                r[j] = fmaf(acc, inv3[ft], bias3[ft]);
            }
            short8 r8;
#pragma unroll
            for (int j = 0; j < 8; ++j) r8[j] = (short)f2bf(r[j]);
            bf16* dst = (s < 2)
                ? qkdst + (((size_t)b_l * 2 + s) * C_ + c) * N_
                : vdst + ((size_t)b_l * C_ + c) * N_;
            *(short8*)(dst + n0) = r8;
        }
    }
}

// ---------------------------------------------------------------------------
// Gram partials via MFMA (T2 swizzle + gload_lds):
//   part[s][bh][d*64+e] = sum_{n in split s} q[d,n]*k[e,n]
// ---------------------------------------------------------------------------
__global__ __launch_bounds__(256) void gram_mfma_kernel(
    const bf16* __restrict__ qk, float* __restrict__ part, int bhTot)
{
    __shared__ bf16 qs[64 * 64];
    __shared__ bf16 ks[64 * 64];
    int bid = blockIdx.x;                 // bhTot*SPLIT
    int s = bid % SPLIT; int bh = bid / SPLIT;
    int h = bh % NH; int b_l = bh / NH;
    const bf16* qp = qk + (((size_t)b_l * 2 + 0) * C_ + h * HD) * N_;
    const bf16* kp = qk + (((size_t)b_l * 2 + 1) * C_ + h * HD) * N_;
    int t = threadIdx.x;
    int w = t >> 6, l = t & 63;
    int r16 = l & 15, kg = l >> 4;
    int wr = w >> 1, wc = w & 1;
    int rsub = l >> 3;
    int colp = ((l & 7) ^ rsub) * 8;      // pre-swizzled n-element offset
    int n0 = s * (N_ / SPLIT);

    f32x4 acc[2][2];
#pragma unroll
    for (int i = 0; i < 2; ++i)
#pragma unroll
        for (int j = 0; j < 2; ++j) acc[i][j] = (f32x4){0.f, 0.f, 0.f, 0.f};

    for (int nc = 0; nc < N_ / SPLIT; nc += 64) {
        int nb = n0 + nc;
#pragma unroll
        for (int i = 0; i < 2; ++i) {
            int row = i * 32 + w * 8 + rsub;
            load_lds16(qp + (size_t)row * N_ + nb + colp, (char*)qs + i * 4096 + t * 16);
            load_lds16(kp + (size_t)row * N_ + nb + colp, (char*)ks + i * 4096 + t * 16);
        }
        __syncthreads();
#pragma unroll
        for (int ksb = 0; ksb < 2; ++ksb) {
            short8 af[2], bfv[2];
#pragma unroll
            for (int mi = 0; mi < 2; ++mi) {
                int row = wr * 32 + mi * 16 + r16;
                int off = row * 128 + ((ksb * 64 + kg * 16) ^ ((row & 7) << 4));
                af[mi] = *(const short8*)((const char*)qs + off);
            }
#pragma unroll
            for (int nj = 0; nj < 2; ++nj) {
                int row = wc * 32 + nj * 16 + r16;
                int off = row * 128 + ((ksb * 64 + kg * 16) ^ ((row & 7) << 4));
                bfv[nj] = *(const short8*)((const char*)ks + off);
            }
#pragma unroll
            for (int mi = 0; mi < 2; ++mi)
#pragma unroll
                for (int nj = 0; nj < 2; ++nj)
                    acc[mi][nj] = __builtin_amdgcn_mfma_f32_16x16x32_bf16(
                        af[mi], bfv[nj], acc[mi][nj], 0, 0, 0);
        }
        __syncthreads();
    }
    float* pp = part + ((size_t)s * bhTot + bh) * 4096;
#pragma unroll
    for (int mi = 0; mi < 2; ++mi)
#pragma unroll
        for (int nj = 0; nj < 2; ++nj) {
            int e = wc * 32 + nj * 16 + r16;
#pragma unroll
            for (int r = 0; r < 4; ++r) {
                int d = wr * 32 + mi * 16 + kg * 4 + r;
                pp[d * 64 + e] = acc[mi][nj][r];
            }
        }
}

// ---------------------------------------------------------------------------
// Softmax, one block per bh (256 threads). Thread t owns elements
// [16t, 16t+16) = row d=t/4, e-range (t%4)*16..+16. Row reduce via
// shfl_xor(1/2); LDS transpose [64][65]; coalesced float4 PT write.
// ---------------------------------------------------------------------------
__global__ __launch_bounds__(256) void softmax_kernel(
    const float* __restrict__ part, float* __restrict__ PT, int bhTot)
{
    __shared__ float tr[64][65];
    int bh = blockIdx.x;
    int t = threadIdx.x;
    int d = t >> 2;                       // 0..63
    int e0 = (t & 3) * 16;
    size_t base = (size_t)bh * 4096 + (size_t)t * 16;   // == d*64 + e0
    float val[16];
#pragma unroll
    for (int j = 0; j < 16; j += 4) {
        float4 a = *(const float4*)&part[base + j];
        val[j] = a.x; val[j+1] = a.y; val[j+2] = a.z; val[j+3] = a.w;
    }
    for (int s = 1; s < SPLIT; ++s) {
        size_t off = (size_t)s * bhTot * 4096 + base;
#pragma unroll
        for (int j = 0; j < 16; j += 4) {
            float4 a = *(const float4*)&part[off + j];
            val[j] += a.x; val[j+1] += a.y; val[j+2] += a.z; val[j+3] += a.w;
        }
    }
    float m = -1e30f;
#pragma unroll
    for (int j = 0; j < 16; ++j) { val[j] *= 0.125f; m = fmaxf(m, val[j]); }
    m = fmaxf(m, __shfl_xor(m, 1));
    m = fmaxf(m, __shfl_xor(m, 2));
    float sum = 0.f;
#pragma unroll
    for (int j = 0; j < 16; ++j) { val[j] = expf(val[j] - m); sum += val[j]; }
    sum += __shfl_xor(sum, 1);
    sum += __shfl_xor(sum, 2);
    float inv = 1.f / sum;
#pragma unroll
    for (int j = 0; j < 16; ++j) tr[e0 + j][d] = val[j] * inv;
    __syncthreads();
    float* op = PT + (size_t)bh * 4096 + (size_t)t * 16;
    int e = t >> 2, d0 = (t & 3) * 16;
#pragma unroll
    for (int j = 0; j < 16; j += 4) {
        float4 r;
        r.x = tr[e][d0+j];   r.y = tr[e][d0+j+1];
        r.z = tr[e][d0+j+2]; r.w = tr[e][d0+j+3];
        *(float4*)(op + j) = r;
    }
}

// ---------------------------------------------------------------------------
// outA[b_l][d][h][n] = sum_e PT[e][d] * v[b_l][h*64+e][n]   (bf16 out)
// 128-px tile per block: PT (16KB) staged once serves 2x the output.
// ---------------------------------------------------------------------------
__global__ __launch_bounds__(256) void pv_kernel(
    const bf16* __restrict__ v, const float* __restrict__ PT,
    bf16* __restrict__ outA)
{
    __shared__ float pts[4096];           // PT[e][d] 16KB
    __shared__ bf16 vs[64 * 128];         // vs[e][n] 16KB
    int bid = blockIdx.x;                 // bhTot*25
    int nt = bid % 25; int bh = bid / 25;
    int h = bh % NH, b_l = bh / NH;
    int t = threadIdx.x;
    int nbase = nt * 128;                 // nt=24 tile is partial (3072..3135)
    const float* ptg = PT + (size_t)bh * 4096;
#pragma unroll
    for (int i = 0; i < 4; ++i)
        load_lds16(ptg + i * 1024 + t * 4, (char*)pts + i * 4096 + t * 16);
    const bf16* vb = v + ((size_t)b_l * C_ + h * HD) * N_;
#pragma unroll
    for (int i = 0; i < 4; ++i) {
        int row = i * 16 + (t >> 4);      // e row 0..63
        int n = nbase + (t & 15) * 8;
        if (n > N_ - 8) n = N_ - 8;       // clamp source (dup cols unused)
        load_lds16(vb + (size_t)row * N_ + n,
                   (char*)vs + i * 4096 + (t >> 4) * 256 + (t & 15) * 16);
    }
    __syncthreads();

    int ng = t & 31, dg = t >> 5;         // n-sub = ng*4 (0..127), d0 = dg*8
    float acc[8][4] = {};
#pragma unroll 8
    for (int e = 0; e < 64; ++e) {
        float4 p0 = *(const float4*)&pts[e * 64 + dg * 8];
        float4 p1 = *(const float4*)&pts[e * 64 + dg * 8 + 4];
        ushort4 vv = *(const ushort4*)&vs[e * 128 + ng * 4];
        float v0 = bf2f(vv.x), v1 = bf2f(vv.y), v2 = bf2f(vv.z), v3 = bf2f(vv.w);
        float p8[8] = {p0.x, p0.y, p0.z, p0.w, p1.x, p1.y, p1.z, p1.w};
#pragma unroll
        for (int i = 0; i < 8; ++i) {
            acc[i][0] = fmaf(p8[i], v0, acc[i][0]);
            acc[i][1] = fmaf(p8[i], v1, acc[i][1]);
            acc[i][2] = fmaf(p8[i], v2, acc[i][2]);
            acc[i][3] = fmaf(p8[i], v3, acc[i][3]);
        }
    }
    if (nbase + ng * 4 < N_) {            // 4-aligned, N_ % 4 == 0
        bf16* op = outA + (size_t)b_l * (C_*N_) + (size_t)h * N_ + nbase + ng * 4;
#pragma unroll
        for (int i = 0; i < 8; ++i) {
            ushort4 r4;
            unsigned short* rr = (unsigned short*)&r4;
            rr[0] = f2bf(acc[i][0]); rr[1] = f2bf(acc[i][1]);
            rr[2] = f2bf(acc[i][2]); rr[3] = f2bf(acc[i][3]);
            *(ushort4*)(op + (size_t)(dg * 8 + i) * (NH*N_)) = r4;
        }
    }
}

// ---------------------------------------------------------------------------
// Convert projection weights f32 -> bf16 (512x512).
// ---------------------------------------------------------------------------
__global__ __launch_bounds__(256) void wconv_kernel(
    const float* __restrict__ w, bf16* __restrict__ wb)
{
    int i = blockIdx.x * 256 + threadIdx.x;   // 262144 total
    wb[i] = f2bf(w[i]);
}

// ---------------------------------------------------------------------------
// MFMA projection, 8 waves, tile 128(co) x 256(n), single-buffered LDS
// (48KB), XCD-chunked swizzle with mt fastest. (Single buffer + implicit
// multi-block overlap is the local optimum for this shape.)
//   out[b0+b_l][co][n] = sum_c Wb[co][c]*A[b_l][n][c] + pb[co]
// ---------------------------------------------------------------------------
__global__ __launch_bounds__(512) void proj_mfma_kernel(
    const bf16* __restrict__ A, const bf16* __restrict__ Wb,
    const float* __restrict__ bias, float* __restrict__ out, int b0, int nwg)
{
    __shared__ bf16 Ws_s[128 * 64];       // 16 KB
    __shared__ bf16 As_s[256 * 64];       // 32 KB
    int bid = blockIdx.x;                 // nwg = nb*52, nwg % 8 == 0
    int cpx = nwg >> 3;                   // chunk per XCD (104: % 4 == 0)
    int swz = (bid & 7) * cpx + (bid >> 3);
    int b_l = swz / 52; int rem = swz % 52;
    int nt = rem >> 2, mt = rem & 3;      // mt fastest: A-quad on one XCD
    int m0 = mt * 128, n0 = nt * 256;     // nt in 0..12
    int t = threadIdx.x;
    int w = t >> 6, l = t & 63;
    int r16 = l & 15, kg = l >> 4;        // frag row / k-group
    int wr = w >> 2, wc = w & 3;          // wave quadrant: 2 co x 4 n
    const bf16* Ab = A + (size_t)b_l * N_ * C_;
    int srow = t >> 3;                    // staging row within 64-row chunk
    int colp = ((t & 7) ^ (srow & 7)) * 8;// pre-swizzled k-element offset

    f32x4 acc[4][4];
#pragma unroll
    for (int i = 0; i < 4; ++i)
#pragma unroll
        for (int j = 0; j < 4; ++j) acc[i][j] = (f32x4){0.f, 0.f, 0.f, 0.f};

    for (int k0 = 0; k0 < C_; k0 += 64) {
#pragma unroll
        for (int i = 0; i < 2; ++i) {
            int row = i * 64 + srow;
            load_lds16(Wb + (size_t)(m0 + row) * C_ + k0 + colp,
                       (char*)Ws_s + i * 8192 + t * 16);
        }
#pragma unroll
        for (int i = 0; i < 4; ++i) {
            int row = i * 64 + srow;
            int nn = n0 + row; if (nn >= N_) nn = N_ - 1;
            load_lds16(Ab + (size_t)nn * C_ + k0 + colp,
                       (char*)As_s + i * 8192 + t * 16);
        }
        __syncthreads();
#pragma unroll
        for (int ks = 0; ks < 2; ++ks) {
            short8 af[4], bfv[4];
#pragma unroll
            for (int mi = 0; mi < 4; ++mi) {
                int row = wr * 64 + mi * 16 + r16;
                int off = row * 128 + ((ks * 64 + kg * 16) ^ ((row & 7) << 4));
                af[mi] = *(const short8*)((const char*)Ws_s + off);
            }
#pragma unroll
            for (int nj = 0; nj < 4; ++nj) {
                int row = wc * 64 + nj * 16 + r16;
                int off = row * 128 + ((ks * 64 + kg * 16) ^ ((row & 7) << 4));
                bfv[nj] = *(const short8*)((const char*)As_s + off);
            }
#pragma unroll
            for (int mi = 0; mi < 4; ++mi)
#pragma unroll
                for (int nj = 0; nj < 4; ++nj)
                    acc[mi][nj] = __builtin_amdgcn_mfma_f32_16x16x32_bf16(
                        af[mi], bfv[nj], acc[mi][nj], 0, 0, 0);
        }
        __syncthreads();
    }
    float* ob = out + ((size_t)(b0 + b_l) * C_) * N_;
#pragma unroll
    for (int mi = 0; mi < 4; ++mi) {
        int cobase = m0 + wr * 64 + mi * 16 + kg * 4;
#pragma unroll
        for (int r = 0; r < 4; ++r) {
            int co = cobase + r;
            float bi = bias[co];
#pragma unroll
            for (int nj = 0; nj < 4; ++nj) {
                int n = n0 + wc * 64 + nj * 16 + r16;
                if (n < N_) ob[(size_t)co * N_ + n] = acc[mi][nj][r] + bi;
            }
        }
    }
}

extern "C" void kernel_launch(void* const* d_in, const int* in_sizes, int n_in,
                              void* d_out, int out_size, void* d_ws, size_t ws_size,
                              hipStream_t stream) {
    const float* x     = (const float*)d_in[0];
    const float* cw    = (const float*)d_in[1];
    const float* gamma = (const float*)d_in[2];
    const float* beta  = (const float*)d_in[3];
    const float* mean  = (const float*)d_in[4];
    const float* var   = (const float*)d_in[5];
    const float* pw    = (const float*)d_in[6];
    const float* pb    = (const float*)d_in[7];
    float* out = (float*)d_out;
    char* wsp = (char*)d_ws;

    const size_t W_B = (size_t)C_ * C_ * sizeof(bf16);              // 524,288

    // Single-pass (all 16 batches) if workspace allows; else two passes of 8.
    size_t qk16   = (size_t)16 * 2 * C_ * N_ * sizeof(bf16);        // 102.8 MB
    size_t v16    = (size_t)16 * C_ * N_ * sizeof(bf16);            //  51.4 MB
    size_t part16 = (size_t)SPLIT * 16 * NH * 4096 * 4;             //  14.7 MB
    size_t pt16   = (size_t)16 * NH * 4096 * 4;                     //   2.1 MB

    int nbs[2]; int ngroups;
    if (ws_size >= qk16 + v16 + part16 + pt16 + W_B) {
        ngroups = 1; nbs[0] = 16;
    } else {
        ngroups = 2; nbs[0] = 8; nbs[1] = 8;
    }

    int b0 = 0;
    for (int gi = 0; gi < ngroups; ++gi) {
        int nb = nbs[gi];
        size_t QK_B   = (size_t)nb * 2 * C_ * N_ * sizeof(bf16);
        size_t V_B    = (size_t)nb * C_ * N_ * sizeof(bf16);
        size_t PART_B = (size_t)SPLIT * nb * NH * 4096 * 4;
        size_t PT_B   = (size_t)nb * NH * 4096 * 4;
        bf16*  qk   = (bf16*)wsp;
        bf16*  v    = (bf16*)(wsp + QK_B);
        float* part = (float*)(wsp + QK_B + V_B);
        float* PT   = (float*)(wsp + QK_B + V_B + PART_B);
        bf16*  Wbf  = (bf16*)(wsp + QK_B + V_B + PART_B + PT_B);
        bf16*  outA = qk;                  // reuse q,k region after gram
        int bhTot = nb * NH;

        if (gi == 0)
            wconv_kernel<<<(C_ * C_) / 256, 256, 0, stream>>>(pw, Wbf);

        conv_bn_kernel<<<nb * C_, 448, 0, stream>>>(
            x, cw, gamma, beta, mean, var, qk, v, b0);
        gram_mfma_kernel<<<bhTot * SPLIT, 256, 0, stream>>>(qk, part, bhTot);
        softmax_kernel<<<bhTot, 256, 0, stream>>>(part, PT, bhTot);
        pv_kernel<<<bhTot * 25, 256, 0, stream>>>(v, PT, outA);
        proj_mfma_kernel<<<nb * 52, 512, 0, stream>>>(outA, Wbf, pb, out, b0, nb * 52);
        b0 += nb;
    }
}